// Round 11
// baseline (345.027 us; speedup 1.0000x reference)
//
#include <hip/hip_runtime.h>

typedef unsigned long long ull;
typedef __attribute__((ext_vector_type(8))) short bf16x8;
typedef __attribute__((ext_vector_type(4))) float f32x4;
typedef __attribute__((ext_vector_type(8))) unsigned short u16x8;

#define DECAY 0.99f
#define BETA 0.25f
#define EPSV 1e-5f
#define EPSGAP 0.0625f
#define THR3 0.03125f

// z: [32, 256, 32, 32] fp32 ; embedding: [1024, 256] ; N = 32*32*32 = 32768
#define Dd 256
#define Kk 1024
#define Nn 32768
#define ZELEM 8388608

__device__ __forceinline__ unsigned short f2bf(float f) {
    unsigned int x = __float_as_uint(f);
    x += 0x7FFFu + ((x >> 16) & 1u);          // RNE
    return (unsigned short)(x >> 16);
}
__device__ __forceinline__ float bf2f(unsigned short b) {
    return __uint_as_float(((unsigned int)b) << 16);
}
__device__ __forceinline__ unsigned mono(unsigned b) {
    return b ^ (((int)b >> 31) | 0x80000000u);   // monotone float->uint
}
__device__ __forceinline__ float unmono(unsigned m) {
    unsigned b = (m & 0x80000000u) ? (m ^ 0x80000000u) : ~m;
    return __uint_as_float(b);
}
__device__ __forceinline__ unsigned umin32(unsigned a, unsigned b) { return a < b ? a : b; }
__device__ __forceinline__ unsigned umax32(unsigned a, unsigned b) { return a > b ? a : b; }
__device__ __forceinline__ ull umin64(ull a, ull b) { return a < b ? a : b; }
__device__ __forceinline__ ull umax64(ull a, ull b) { return a > b ? a : b; }

// ---------------------------------------------------------------------------
// Kernel 1 (R11): grid 65. No dw replicas, no hist (dw + counts now
// computed gather-side in dwfin from post-fixup idx).
//  blocks 0..63 : emb hi/lo split + esq; block 0 zeroes flagcnt/loss_fix
//  block 64     : reduce sum(ema_cs) -> nsum (sum(counts)=32768 invariant)
__global__ __launch_bounds__(256) void prep_e_kernel(
        const float* __restrict__ emb, unsigned short* __restrict__ ehg,
        unsigned short* __restrict__ elg, float* __restrict__ esq,
        int* __restrict__ flagcnt, float* __restrict__ loss_fix,
        float* __restrict__ nsum, const float* __restrict__ ema_cs) {
    const int nsub = blockIdx.x;
    const int t = threadIdx.x;
    if (nsub < 64) {
        if (nsub == 0 && t == 16) flagcnt[0] = 0;
        if (nsub == 0 && t == 17) loss_fix[0] = 0.0f;
        if (nsub == 0 && t == 18) flagcnt[1] = 0;
        #pragma unroll
        for (int it = 0; it < 2; ++it) {
            const int item = it * 256 + t;
            const int kc = item >> 6, lane = item & 63;
            const int quad = lane >> 4, nl = lane & 15;
            const float* ep = emb + (size_t)(nsub * 16 + nl) * Dd + kc * 32 + quad * 8;
            const float4 a = *(const float4*)ep;
            const float4 b4 = *(const float4*)(ep + 4);
            const float v[8] = {a.x, a.y, a.z, a.w, b4.x, b4.y, b4.z, b4.w};
            u16x8 hi, lo;
            #pragma unroll
            for (int j = 0; j < 8; ++j) {
                const unsigned short h = f2bf(v[j]);
                hi[j] = h;
                lo[j] = f2bf(v[j] - bf2f(h));
            }
            const size_t off = ((size_t)(nsub * 8 + kc) * 64 + lane) * 8;
            *(u16x8*)&ehg[off] = hi;
            *(u16x8*)&elg[off] = lo;
        }
        {
            const int nl = t >> 4, seg = t & 15;
            const float* ep = emb + (size_t)(nsub * 16 + nl) * Dd + seg * 16;
            float s = 0.0f;
            #pragma unroll
            for (int j = 0; j < 4; ++j) {
                const float4 v4 = *(const float4*)(ep + j * 4);
                s += v4.x * v4.x + v4.y * v4.y + v4.z * v4.z + v4.w * v4.w;
            }
            #pragma unroll
            for (int d = 1; d < 16; d <<= 1) s += __shfl_xor(s, d);
            if (seg == 0) esq[nsub * 16 + nl] = s;
        }
    } else {
        __shared__ float wred[4];
        const int w = t >> 6, lane = t & 63;
        float s = ema_cs[t] + ema_cs[t + 256] + ema_cs[t + 512] + ema_cs[t + 768];
        #pragma unroll
        for (int d = 32; d > 0; d >>= 1) s += __shfl_xor(s, d);
        if (lane == 0) wred[w] = s;
        __syncthreads();
        if (t == 0)
            nsum[0] = DECAY * (wred[0] + wred[1] + wred[2] + wred[3])
                      + (1.0f - DECAY) * (float)Nn;
    }
}

// ---------------------------------------------------------------------------
// Kernel 2 (R11): MFMA distance + TOP-3 argmin + flags + loss + fused
// transpose (zf written from staged regs — R1-verified free). Epilogue is
// now LIGHT: no hist atomics, no emb gather, no zq store, no dw atomics
// (dw moved gather-side to dwfin; zq to gather kernel).
__global__ __launch_bounds__(256) void dist_kernel(
        const float* __restrict__ z, const unsigned short* __restrict__ ehg,
        const unsigned short* __restrict__ elg, const float* __restrict__ esq,
        float* __restrict__ zf,
        int* __restrict__ idx_i, float* __restrict__ idx_f,
        int* __restrict__ flagcnt,
        int* __restrict__ listA, int* __restrict__ kkA,
        float* __restrict__ valA, int* __restrict__ listB,
        float* __restrict__ valB, float* __restrict__ loss_p) {
    __shared__ __align__(16) unsigned char smem[72704];
    unsigned short* zh = (unsigned short*)smem;            // 32KB
    unsigned short* zl = (unsigned short*)(smem + 32768);  // 32KB
    ull* mb   = (ull*)(smem + 65536);                      // 2KB
    ull* ms   = (ull*)(smem + 67584);                      // 2KB
    float* zsqp = (float*)(smem + 69632);                  // 1KB
    ull* mt   = (ull*)(smem + 70656);                      // 2KB (top-3)

    const int t = threadIdx.x, w = t >> 6, L = t & 63;
    const int quad = L >> 4, lr = L & 15;
    const int m0 = blockIdx.x * 64;
    const int b = m0 >> 10, hw0 = m0 & 1023;

    // ---- stage: convert to hi/lo bf16 AND write fp32 zf rows (transpose)
    {
        const int c0 = w * 64;
        const float* zp = z + (size_t)b * 262144 + hw0 + L;
        float* zfp = zf + (size_t)(m0 + L) * 256 + c0;
        float s = 0.0f;
        #pragma unroll
        for (int cg = 0; cg < 8; ++cg) {
            float v[8];
            #pragma unroll
            for (int j = 0; j < 8; ++j)
                v[j] = zp[(size_t)(c0 + cg * 8 + j) * 1024];
            *(float4*)(zfp + cg * 8)     = make_float4(v[0], v[1], v[2], v[3]);
            *(float4*)(zfp + cg * 8 + 4) = make_float4(v[4], v[5], v[6], v[7]);
            u16x8 hi, lo;
            #pragma unroll
            for (int j = 0; j < 8; ++j) {
                s = fmaf(v[j], v[j], s);
                const unsigned short h = f2bf(v[j]);
                hi[j] = h;
                lo[j] = f2bf(v[j] - bf2f(h));
            }
            const int chunk = ((c0 >> 3) + cg) ^ (L & 7);
            *(u16x8*)&zh[L * 256 + chunk * 8] = hi;
            *(u16x8*)&zl[L * 256 + chunk * 8] = lo;
        }
        zsqp[L * 4 + w] = s;
    }
    __syncthreads();

    const unsigned short* ehw = ehg + (size_t)(w * 1024 + L) * 8;
    const unsigned short* elw = elg + (size_t)(w * 1024 + L) * 8;

    unsigned bb[16], ss[16], tt[16];
    #pragma unroll
    for (int i = 0; i < 16; ++i) { bb[i] = 0xFFFFFFFFu; ss[i] = 0xFFFFFFFFu; tt[i] = 0xFFFFFFFFu; }

    bf16x8 Bh[2][2], Bl[2][2];
    #pragma unroll
    for (int ni = 0; ni < 2; ++ni) {
        Bh[0][ni] = *(const bf16x8*)(ehw + (size_t)ni * 4096);
        Bl[0][ni] = *(const bf16x8*)(elw + (size_t)ni * 4096);
    }
    bf16x8 Ah[2][4], Al[2][4];
    #pragma unroll
    for (int mi = 0; mi < 4; ++mi) {
        const int chunk = quad ^ (lr & 7);               // kc = 0
        const int o = (mi * 16 + lr) * 256 + chunk * 8;
        Ah[0][mi] = *(const bf16x8*)&zh[o];
        Al[0][mi] = *(const bf16x8*)&zl[o];
    }

    for (int nt = 0; nt < 8; ++nt) {
        f32x4 acc[4][2];
        #pragma unroll
        for (int mi = 0; mi < 4; ++mi)
            #pragma unroll
            for (int ni = 0; ni < 2; ++ni) acc[mi][ni] = (f32x4){0.f, 0.f, 0.f, 0.f};

        #pragma unroll
        for (int kc = 0; kc < 8; ++kc) {
            const int cur = kc & 1, nxt = cur ^ 1;
            const int nkc = (kc + 1) & 7;
            const int nnt = (kc == 7) ? ((nt + 1) & 7) : nt;
            #pragma unroll
            for (int ni = 0; ni < 2; ++ni) {
                const size_t o = (size_t)nnt * 32768 + (size_t)ni * 4096 + (size_t)nkc * 512;
                Bh[nxt][ni] = *(const bf16x8*)(ehw + o);
                Bl[nxt][ni] = *(const bf16x8*)(elw + o);
            }
            #pragma unroll
            for (int mi = 0; mi < 4; ++mi) {
                const int chunk = (nkc * 4 + quad) ^ (lr & 7);
                const int o = (mi * 16 + lr) * 256 + chunk * 8;
                Ah[nxt][mi] = *(const bf16x8*)&zh[o];
                Al[nxt][mi] = *(const bf16x8*)&zl[o];
            }
            __builtin_amdgcn_s_setprio(1);
            #pragma unroll
            for (int mi = 0; mi < 4; ++mi)
                #pragma unroll
                for (int ni = 0; ni < 2; ++ni) {
                    acc[mi][ni] = __builtin_amdgcn_mfma_f32_16x16x32_bf16(Ah[cur][mi], Bh[cur][ni], acc[mi][ni], 0, 0, 0);
                    acc[mi][ni] = __builtin_amdgcn_mfma_f32_16x16x32_bf16(Ah[cur][mi], Bl[cur][ni], acc[mi][ni], 0, 0, 0);
                    acc[mi][ni] = __builtin_amdgcn_mfma_f32_16x16x32_bf16(Al[cur][mi], Bh[cur][ni], acc[mi][ni], 0, 0, 0);
                }
            __builtin_amdgcn_s_setprio(0);
        }
        const int q0 = nt * 8 + w * 2;
        const float e0b = esq[q0 * 16 + lr] + 512.0f;
        const float e1b = esq[(q0 + 1) * 16 + lr] + 512.0f;
        #pragma unroll
        for (int mi = 0; mi < 4; ++mi)
            #pragma unroll
            for (int reg = 0; reg < 4; ++reg) {
                const int i = mi * 4 + reg;
                #pragma unroll
                for (int ni = 0; ni < 2; ++ni) {
                    const float val = fmaf(-2.0f, acc[mi][ni][reg], ni ? e1b : e0b);
                    const unsigned pk = (__float_as_uint(val) & 0xFFFFFFC0u) | (unsigned)(q0 + ni);
                    const unsigned m1 = umin32(bb[i], pk), M1 = umax32(bb[i], pk);
                    const unsigned m2 = umin32(ss[i], M1), M2 = umax32(ss[i], M1);
                    const unsigned m3 = umin32(tt[i], M2);
                    bb[i] = m1; ss[i] = m2; tt[i] = m3;
                }
            }
    }

    #pragma unroll
    for (int mi = 0; mi < 4; ++mi)
        #pragma unroll
        for (int reg = 0; reg < 4; ++reg) {
            const int i = mi * 4 + reg;
            ull b2 = ((ull)(bb[i] & 0xFFFFFFC0u) << 14) | (ull)((bb[i] & 63u) * 16 + lr);
            ull s2 = ((ull)(ss[i] & 0xFFFFFFC0u) << 14) | (ull)((ss[i] & 63u) * 16 + lr);
            ull t2 = ((ull)(tt[i] & 0xFFFFFFC0u) << 14) | (ull)((tt[i] & 63u) * 16 + lr);
            #pragma unroll
            for (int d = 1; d < 16; d <<= 1) {
                const ull ob = __shfl_xor(b2, d);
                const ull os = __shfl_xor(s2, d);
                const ull ot = __shfl_xor(t2, d);
                const ull x1 = umin64(b2, ob), y1 = umax64(b2, ob);
                const ull x2 = umin64(s2, os), y2 = umax64(s2, os);
                const ull c2 = umin64(y1, x2);
                const ull t1 = umax64(y1, x2);
                const ull c3 = umin64(t1, umin64(y2, umin64(t2, ot)));
                b2 = x1; s2 = c2; t2 = c3;
            }
            if (lr == 0) {
                const int row = mi * 16 + quad * 4 + reg;
                mb[w * 64 + row] = b2;
                ms[w * 64 + row] = s2;
                mt[w * 64 + row] = t2;
            }
        }
    __syncthreads();

    if (t < 64) {
        ull b2 = mb[t], s2 = ms[t], t2 = mt[t];
        #pragma unroll
        for (int ww = 1; ww < 4; ++ww) {
            const ull ob = mb[ww * 64 + t], os = ms[ww * 64 + t], ot = mt[ww * 64 + t];
            const ull x1 = umin64(b2, ob), y1 = umax64(b2, ob);
            const ull x2 = umin64(s2, os), y2 = umax64(s2, os);
            const ull c2 = umin64(y1, x2);
            const ull t1 = umax64(y1, x2);
            const ull c3 = umin64(t1, umin64(y2, umin64(t2, ot)));
            b2 = x1; s2 = c2; t2 = c3;
        }
        const int k1 = (int)(b2 & 16383ull);
        const int k2 = (int)(s2 & 16383ull);
        const float v1 = __uint_as_float((unsigned)(b2 >> 14)) - 512.0f;
        const float v2 = __uint_as_float((unsigned)(s2 >> 14)) - 512.0f;
        const float v3 = __uint_as_float((unsigned)(t2 >> 14)) - 512.0f;
        idx_i[m0 + t] = k1;
        idx_f[m0 + t] = (float)k1;
        if (v2 - v1 < EPSGAP) {
            if (v3 - v1 < THR3) {
                const int pos = atomicAdd(&flagcnt[1], 1);
                listB[pos] = m0 + t;
                valB[pos] = v1;
            } else {
                const int pos = atomicAdd(&flagcnt[0], 1);
                listA[pos] = m0 + t;
                kkA[pos] = k1 | (k2 << 16);
                valA[pos] = v1;
            }
        }
        float lp = v1 + zsqp[t * 4] + zsqp[t * 4 + 1] + zsqp[t * 4 + 2] + zsqp[t * 4 + 3];
        #pragma unroll
        for (int d = 32; d > 0; d >>= 1) lp += __shfl_down(lp, d);
        if (t == 0) loss_p[blockIdx.x] = lp;
    }
}

// ---------------------------------------------------------------------------
// Kernel 3 (R11): two-class fixup — patches idx_i/idx_f/loss_fix ONLY.
// (dw and counts are derived from post-fixup idx in dwfin; zq in gather.)
// Reads zf (coalesced) instead of z (strided).
__global__ __launch_bounds__(256) void fixup_kernel(
        const float* __restrict__ zf, const float* __restrict__ emb,
        const float* __restrict__ esq, const int* __restrict__ flagcnt,
        const int* __restrict__ listA, const int* __restrict__ kkA,
        const float* __restrict__ valA, const int* __restrict__ listB,
        const float* __restrict__ valB,
        int* __restrict__ idx_i, float* __restrict__ idx_f,
        float* __restrict__ loss_fix) {
    __shared__ float zrow[256];
    __shared__ float red1[4], red2[4];
    __shared__ ull red[256];
    const int t = threadIdx.x;
    const int w = t >> 6, lane = t & 63;

    // ---- Phase A: exact 2-way check (k1 vs k2) -------------------------
    const int totalA = flagcnt[0];
    for (int fi = blockIdx.x; fi < totalA; fi += 512) {
        const int n = listA[fi];
        const int kk = kkA[fi];
        const int k1 = kk & 0xFFFF, k2 = kk >> 16;
        const float zv = zf[(size_t)n * Dd + t];
        float c1 = zv * emb[(size_t)k1 * Dd + t];
        float c2 = zv * emb[(size_t)k2 * Dd + t];
        #pragma unroll
        for (int d = 32; d > 0; d >>= 1) {
            c1 += __shfl_xor(c1, d);
            c2 += __shfl_xor(c2, d);
        }
        __syncthreads();
        if (lane == 0) { red1[w] = c1; red2[w] = c2; }
        __syncthreads();
        if (t == 0) {
            const float d1 = esq[k1] - 2.0f * (red1[0] + red1[1] + red1[2] + red1[3]);
            const float d2 = esq[k2] - 2.0f * (red2[0] + red2[1] + red2[2] + red2[3]);
            const ull p1 = ((ull)mono(__float_as_uint(d1)) << 32) | (unsigned)k1;
            const ull p2 = ((ull)mono(__float_as_uint(d2)) << 32) | (unsigned)k2;
            const ull pb = p1 < p2 ? p1 : p2;
            const int knew = (int)(unsigned)(pb & 0xFFFFFFFFull);
            const float vnew = unmono((unsigned)(pb >> 32));
            if (knew != k1) {
                idx_i[n] = knew;
                idx_f[n] = (float)knew;
            }
            atomicAdd(loss_fix, vnew - valA[fi]);
        }
    }

    // ---- Phase B: full-K exact rescan (rare) ---------------------------
    const int totalB = flagcnt[1];
    for (int fi = blockIdx.x; fi < totalB; fi += 512) {
        const int n = listB[fi];
        __syncthreads();
        zrow[t] = zf[(size_t)n * Dd + t];
        __syncthreads();
        ull best = ~0ull;
        #pragma unroll
        for (int kc = 0; kc < 4; ++kc) {
            const int k = t * 4 + kc;
            const float* ep = emb + (size_t)k * Dd;
            float dot = 0.0f;
            #pragma unroll 8
            for (int c4 = 0; c4 < 64; ++c4) {
                const float4 e4 = *(const float4*)(ep + c4 * 4);
                const float4 z4 = *(const float4*)&zrow[c4 * 4];
                dot = fmaf(z4.x, e4.x, dot);
                dot = fmaf(z4.y, e4.y, dot);
                dot = fmaf(z4.z, e4.z, dot);
                dot = fmaf(z4.w, e4.w, dot);
            }
            const float val = esq[k] - 2.0f * dot;
            const ull pk = ((ull)mono(__float_as_uint(val)) << 32) | (unsigned)k;
            if (pk < best) best = pk;
        }
        red[t] = best;
        __syncthreads();
        for (int s = 128; s > 0; s >>= 1) {
            if (t < s) { if (red[t + s] < red[t]) red[t] = red[t + s]; }
            __syncthreads();
        }
        if (t == 0) {
            const int knew = (int)(unsigned)(red[0] & 0xFFFFFFFFull);
            const float vnew = unmono((unsigned)(red[0] >> 32));
            const int kold = idx_i[n];
            if (knew != kold) {
                idx_i[n] = knew;
                idx_f[n] = (float)knew;
            }
            atomicAdd(loss_fix, vnew - valB[fi]);
        }
    }
}

// ---------------------------------------------------------------------------
// Kernel 4 (R11): gather-side dw + finalize. One block per code k:
// parallel match-scan of idx into an LDS list (16 segments of 2048), then
// coalesced accumulation of matching zf rows. cnt = hist[k] (post-fixup,
// so no hist array / patches needed anywhere). Then EMA + Laplace + divide.
// Block 0 reduces the loss.
__global__ __launch_bounds__(256) void dwfin_kernel(
        const int* __restrict__ idx, const float* __restrict__ zf,
        const float* __restrict__ ema_w, const float* __restrict__ ema_cs,
        const float* __restrict__ nsum, const float* __restrict__ loss_p,
        const float* __restrict__ loss_fix,
        float* __restrict__ cs_out, float* __restrict__ loss_out,
        float* __restrict__ new_emb_out, float* __restrict__ new_ema_w_out) {
    __shared__ int list[2048];
    __shared__ int lcnt;
    const int k = blockIdx.x;
    const int t = threadIdx.x;
    float acc = 0.0f;
    int cnt = 0;
    for (int seg = 0; seg < Nn; seg += 2048) {
        __syncthreads();
        if (t == 0) lcnt = 0;
        __syncthreads();
        #pragma unroll
        for (int j = 0; j < 8; ++j) {
            const int n = seg + j * 256 + t;
            if (idx[n] == k) list[atomicAdd(&lcnt, 1)] = n;
        }
        __syncthreads();
        const int m = lcnt;
        cnt += m;
        #pragma unroll 4
        for (int i = 0; i < m; ++i)
            acc += zf[(size_t)list[i] * Dd + t];
    }
    const float n = nsum[0];
    const float csr = ema_cs[k] * DECAY + (1.0f - DECAY) * (float)cnt;
    const float cs = (csr + EPSV) / (n + (float)Kk * EPSV) * n;
    if (t == 0) cs_out[k] = cs;
    const int i = k * 256 + t;
    const float nw = ema_w[i] * DECAY + (1.0f - DECAY) * acc;
    new_ema_w_out[i] = nw;
    new_emb_out[i]   = nw / cs;
    if (k == 0) {
        __shared__ float wred[4];
        const int w = t >> 6, lane = t & 63;
        float r2 = loss_p[t] + loss_p[t + 256];
        #pragma unroll
        for (int d = 32; d > 0; d >>= 1) r2 += __shfl_xor(r2, d);
        if (lane == 0) wred[w] = r2;
        __syncthreads();
        if (t == 0)
            loss_out[0] = BETA * (wred[0] + wred[1] + wred[2] + wred[3]
                                  + loss_fix[0]) / (float)ZELEM;
    }
}

// ---------------------------------------------------------------------------
// Kernel 5: gather z_q in [B,C,HW] layout, overwriting the zf region.
// Runs last (after fixup's idx patches and dwfin's zf reads). R0-R3 verified.
__global__ __launch_bounds__(256) void gather_kernel(
        const float* __restrict__ emb, const int* __restrict__ idx,
        float* __restrict__ zq_out) {
    const int tid = blockIdx.x * 256 + threadIdx.x;
    const int e0 = tid * 4;
    const int c = (e0 >> 10) & 255;
    const int b = e0 >> 18;
    const int n0 = b * 1024 + (e0 & 1023);
    const int4 j4 = *(const int4*)(idx + n0);
    float4 e;
    e.x = emb[(size_t)j4.x * Dd + c];
    e.y = emb[(size_t)j4.y * Dd + c];
    e.z = emb[(size_t)j4.z * Dd + c];
    e.w = emb[(size_t)j4.w * Dd + c];
    *(float4*)(zq_out + e0) = e;
}

// ---------------------------------------------------------------------------
extern "C" void kernel_launch(void* const* d_in, const int* in_sizes, int n_in,
                              void* d_out, int out_size, void* d_ws, size_t ws_size,
                              hipStream_t stream) {
    const float* z      = (const float*)d_in[0];
    const float* emb    = (const float*)d_in[1];
    const float* ema_cs = (const float*)d_in[2];
    const float* ema_w  = (const float*)d_in[3];

    float* out = (float*)d_out;
    float* zq_out        = out;                 // 8388608 (zf staging until gather)
    float* idx_out_f     = out + 8388608;       // 32768
    float* loss_out      = out + 8421376;       // 1
    float* new_emb_out   = out + 8421377;       // 262144
    float* cs_out        = out + 8683521;       // 1024
    float* new_ema_w_out = out + 8684545;       // 262144

    int*   idx_i    = (int*)d_ws;                    // 32768
    int*   flagcnt  = idx_i + 32768;                 // 16  ([0]=A, [1]=B)
    float* loss_fix = (float*)(flagcnt + 16);        // 16
    int*   listA    = (int*)(loss_fix + 16);         // 32768
    float* valA     = (float*)(listA + 32768);       // 32768
    int*   kkA      = (int*)(valA + 32768);          // 32768
    int*   listB    = kkA + 32768;                   // 32768
    float* valB     = (float*)(listB + 32768);       // 32768
    float* esq      = valB + 32768;                  // 1024
    float* loss_p   = esq + 1024;                    // 512
    float* nsum     = loss_p + 512;                  // 16
    unsigned short* ehg = (unsigned short*)(nsum + 16);     // 262144 shorts
    unsigned short* elg = ehg + 262144;                     // 262144 shorts

    float* zf = zq_out;        // transposed z staged in zq output region

    prep_e_kernel<<<65, 256, 0, stream>>>(emb, ehg, elg, esq, flagcnt,
                                          loss_fix, nsum, ema_cs);
    dist_kernel<<<Nn / 64, 256, 0, stream>>>(z, ehg, elg, esq, zf, idx_i,
                                             idx_out_f, flagcnt, listA, kkA,
                                             valA, listB, valB, loss_p);
    fixup_kernel<<<512, 256, 0, stream>>>(zf, emb, esq, flagcnt, listA, kkA,
                                          valA, listB, valB, idx_i, idx_out_f,
                                          loss_fix);
    dwfin_kernel<<<Kk, 256, 0, stream>>>(idx_i, zf, ema_w, ema_cs, nsum,
                                         loss_p, loss_fix, cs_out, loss_out,
                                         new_emb_out, new_ema_w_out);
    gather_kernel<<<ZELEM / 1024, 256, 0, stream>>>(emb, idx_i, zq_out);
}

// Round 12
// 245.047 us; speedup vs baseline: 1.4080x; 1.4080x over previous
//
#include <hip/hip_runtime.h>

typedef unsigned long long ull;
typedef __attribute__((ext_vector_type(8))) short bf16x8;
typedef __attribute__((ext_vector_type(4))) float f32x4;
typedef __attribute__((ext_vector_type(8))) unsigned short u16x8;

#define DECAY 0.99f
#define BETA 0.25f
#define EPSV 1e-5f
#define EPSGAP 0.0625f
#define THR3 0.03125f

// z: [32, 256, 32, 32] fp32 ; embedding: [1024, 256] ; N = 32*32*32 = 32768
#define Dd 256
#define Kk 1024
#define Nn 32768
#define ZELEM 8388608

__device__ __forceinline__ unsigned short f2bf(float f) {
    unsigned int x = __float_as_uint(f);
    x += 0x7FFFu + ((x >> 16) & 1u);          // RNE
    return (unsigned short)(x >> 16);
}
__device__ __forceinline__ float bf2f(unsigned short b) {
    return __uint_as_float(((unsigned int)b) << 16);
}
__device__ __forceinline__ unsigned mono(unsigned b) {
    return b ^ (((int)b >> 31) | 0x80000000u);   // monotone float->uint
}
__device__ __forceinline__ float unmono(unsigned m) {
    unsigned b = (m & 0x80000000u) ? (m ^ 0x80000000u) : ~m;
    return __uint_as_float(b);
}
__device__ __forceinline__ unsigned umin32(unsigned a, unsigned b) { return a < b ? a : b; }
__device__ __forceinline__ unsigned umax32(unsigned a, unsigned b) { return a > b ? a : b; }
__device__ __forceinline__ ull umin64(ull a, ull b) { return a < b ? a : b; }
__device__ __forceinline__ ull umax64(ull a, ull b) { return a > b ? a : b; }

// ---------------------------------------------------------------------------
// Kernel 1: 64 blocks. emb hi/lo split + esq; zero hist/flagcnt/loss_fix/dw.
__global__ __launch_bounds__(256) void prep_e_kernel(
        const float* __restrict__ emb, unsigned short* __restrict__ ehg,
        unsigned short* __restrict__ elg, float* __restrict__ esq,
        int* __restrict__ hist, int* __restrict__ flagcnt,
        float* __restrict__ loss_fix, float* __restrict__ dw) {
    const int nsub = blockIdx.x;
    const int t = threadIdx.x;
    if (t < 16) hist[nsub * 16 + t] = 0;
    if (nsub == 0 && t == 16) flagcnt[0] = 0;
    if (nsub == 0 && t == 17) loss_fix[0] = 0.0f;
    if (nsub == 0 && t == 18) flagcnt[1] = 0;
    {
        float4* dwp = (float4*)dw;
        #pragma unroll
        for (int j = 0; j < 4; ++j)
            dwp[(size_t)(nsub * 256 + t) * 4 + j] = make_float4(0.f, 0.f, 0.f, 0.f);
    }
    #pragma unroll
    for (int it = 0; it < 2; ++it) {
        const int item = it * 256 + t;
        const int kc = item >> 6, lane = item & 63;
        const int quad = lane >> 4, nl = lane & 15;
        const float* ep = emb + (size_t)(nsub * 16 + nl) * Dd + kc * 32 + quad * 8;
        const float4 a = *(const float4*)ep;
        const float4 b4 = *(const float4*)(ep + 4);
        const float v[8] = {a.x, a.y, a.z, a.w, b4.x, b4.y, b4.z, b4.w};
        u16x8 hi, lo;
        #pragma unroll
        for (int j = 0; j < 8; ++j) {
            const unsigned short h = f2bf(v[j]);
            hi[j] = h;
            lo[j] = f2bf(v[j] - bf2f(h));
        }
        const size_t off = ((size_t)(nsub * 8 + kc) * 64 + lane) * 8;
        *(u16x8*)&ehg[off] = hi;
        *(u16x8*)&elg[off] = lo;
    }
    {
        const int nl = t >> 4, seg = t & 15;
        const float* ep = emb + (size_t)(nsub * 16 + nl) * Dd + seg * 16;
        float s = 0.0f;
        #pragma unroll
        for (int j = 0; j < 4; ++j) {
            const float4 v4 = *(const float4*)(ep + j * 4);
            s += v4.x * v4.x + v4.y * v4.y + v4.z * v4.z + v4.w * v4.w;
        }
        #pragma unroll
        for (int d = 1; d < 16; d <<= 1) s += __shfl_xor(s, d);
        if (seg == 0) esq[nsub * 16 + nl] = s;
    }
}

// ---------------------------------------------------------------------------
// Kernel 2: MFMA distance + TOP-3 argmin + hist + flags + loss + fused
// transpose (zf from staged regs — R1-verified ~free). LIGHT epilogue:
// no dw atomics (counting-sort tail), no emb gather / zq store (gather
// kernel at end). R11-dist + hist atomic restored.
__global__ __launch_bounds__(256) void dist_kernel(
        const float* __restrict__ z, const unsigned short* __restrict__ ehg,
        const unsigned short* __restrict__ elg, const float* __restrict__ esq,
        float* __restrict__ zf,
        int* __restrict__ idx_i, float* __restrict__ idx_f,
        int* __restrict__ hist, int* __restrict__ flagcnt,
        int* __restrict__ listA, int* __restrict__ kkA,
        float* __restrict__ valA, int* __restrict__ listB,
        float* __restrict__ valB, float* __restrict__ loss_p) {
    __shared__ __align__(16) unsigned char smem[72704];
    unsigned short* zh = (unsigned short*)smem;            // 32KB
    unsigned short* zl = (unsigned short*)(smem + 32768);  // 32KB
    ull* mb   = (ull*)(smem + 65536);                      // 2KB
    ull* ms   = (ull*)(smem + 67584);                      // 2KB
    float* zsqp = (float*)(smem + 69632);                  // 1KB
    ull* mt   = (ull*)(smem + 70656);                      // 2KB (top-3)

    const int t = threadIdx.x, w = t >> 6, L = t & 63;
    const int quad = L >> 4, lr = L & 15;
    const int m0 = blockIdx.x * 64;
    const int b = m0 >> 10, hw0 = m0 & 1023;

    // ---- stage: hi/lo bf16 conversion AND fp32 zf rows (fused transpose)
    {
        const int c0 = w * 64;
        const float* zp = z + (size_t)b * 262144 + hw0 + L;
        float* zfp = zf + (size_t)(m0 + L) * 256 + c0;
        float s = 0.0f;
        #pragma unroll
        for (int cg = 0; cg < 8; ++cg) {
            float v[8];
            #pragma unroll
            for (int j = 0; j < 8; ++j)
                v[j] = zp[(size_t)(c0 + cg * 8 + j) * 1024];
            *(float4*)(zfp + cg * 8)     = make_float4(v[0], v[1], v[2], v[3]);
            *(float4*)(zfp + cg * 8 + 4) = make_float4(v[4], v[5], v[6], v[7]);
            u16x8 hi, lo;
            #pragma unroll
            for (int j = 0; j < 8; ++j) {
                s = fmaf(v[j], v[j], s);
                const unsigned short h = f2bf(v[j]);
                hi[j] = h;
                lo[j] = f2bf(v[j] - bf2f(h));
            }
            const int chunk = ((c0 >> 3) + cg) ^ (L & 7);
            *(u16x8*)&zh[L * 256 + chunk * 8] = hi;
            *(u16x8*)&zl[L * 256 + chunk * 8] = lo;
        }
        zsqp[L * 4 + w] = s;
    }
    __syncthreads();

    const unsigned short* ehw = ehg + (size_t)(w * 1024 + L) * 8;
    const unsigned short* elw = elg + (size_t)(w * 1024 + L) * 8;

    unsigned bb[16], ss[16], tt[16];
    #pragma unroll
    for (int i = 0; i < 16; ++i) { bb[i] = 0xFFFFFFFFu; ss[i] = 0xFFFFFFFFu; tt[i] = 0xFFFFFFFFu; }

    bf16x8 Bh[2][2], Bl[2][2];
    #pragma unroll
    for (int ni = 0; ni < 2; ++ni) {
        Bh[0][ni] = *(const bf16x8*)(ehw + (size_t)ni * 4096);
        Bl[0][ni] = *(const bf16x8*)(elw + (size_t)ni * 4096);
    }
    bf16x8 Ah[2][4], Al[2][4];
    #pragma unroll
    for (int mi = 0; mi < 4; ++mi) {
        const int chunk = quad ^ (lr & 7);               // kc = 0
        const int o = (mi * 16 + lr) * 256 + chunk * 8;
        Ah[0][mi] = *(const bf16x8*)&zh[o];
        Al[0][mi] = *(const bf16x8*)&zl[o];
    }

    for (int nt = 0; nt < 8; ++nt) {
        f32x4 acc[4][2];
        #pragma unroll
        for (int mi = 0; mi < 4; ++mi)
            #pragma unroll
            for (int ni = 0; ni < 2; ++ni) acc[mi][ni] = (f32x4){0.f, 0.f, 0.f, 0.f};

        #pragma unroll
        for (int kc = 0; kc < 8; ++kc) {
            const int cur = kc & 1, nxt = cur ^ 1;
            const int nkc = (kc + 1) & 7;
            const int nnt = (kc == 7) ? ((nt + 1) & 7) : nt;
            #pragma unroll
            for (int ni = 0; ni < 2; ++ni) {
                const size_t o = (size_t)nnt * 32768 + (size_t)ni * 4096 + (size_t)nkc * 512;
                Bh[nxt][ni] = *(const bf16x8*)(ehw + o);
                Bl[nxt][ni] = *(const bf16x8*)(elw + o);
            }
            #pragma unroll
            for (int mi = 0; mi < 4; ++mi) {
                const int chunk = (nkc * 4 + quad) ^ (lr & 7);
                const int o = (mi * 16 + lr) * 256 + chunk * 8;
                Ah[nxt][mi] = *(const bf16x8*)&zh[o];
                Al[nxt][mi] = *(const bf16x8*)&zl[o];
            }
            __builtin_amdgcn_s_setprio(1);
            #pragma unroll
            for (int mi = 0; mi < 4; ++mi)
                #pragma unroll
                for (int ni = 0; ni < 2; ++ni) {
                    acc[mi][ni] = __builtin_amdgcn_mfma_f32_16x16x32_bf16(Ah[cur][mi], Bh[cur][ni], acc[mi][ni], 0, 0, 0);
                    acc[mi][ni] = __builtin_amdgcn_mfma_f32_16x16x32_bf16(Ah[cur][mi], Bl[cur][ni], acc[mi][ni], 0, 0, 0);
                    acc[mi][ni] = __builtin_amdgcn_mfma_f32_16x16x32_bf16(Al[cur][mi], Bh[cur][ni], acc[mi][ni], 0, 0, 0);
                }
            __builtin_amdgcn_s_setprio(0);
        }
        const int q0 = nt * 8 + w * 2;
        const float e0b = esq[q0 * 16 + lr] + 512.0f;
        const float e1b = esq[(q0 + 1) * 16 + lr] + 512.0f;
        #pragma unroll
        for (int mi = 0; mi < 4; ++mi)
            #pragma unroll
            for (int reg = 0; reg < 4; ++reg) {
                const int i = mi * 4 + reg;
                #pragma unroll
                for (int ni = 0; ni < 2; ++ni) {
                    const float val = fmaf(-2.0f, acc[mi][ni][reg], ni ? e1b : e0b);
                    const unsigned pk = (__float_as_uint(val) & 0xFFFFFFC0u) | (unsigned)(q0 + ni);
                    const unsigned m1 = umin32(bb[i], pk), M1 = umax32(bb[i], pk);
                    const unsigned m2 = umin32(ss[i], M1), M2 = umax32(ss[i], M1);
                    const unsigned m3 = umin32(tt[i], M2);
                    bb[i] = m1; ss[i] = m2; tt[i] = m3;
                }
            }
    }

    #pragma unroll
    for (int mi = 0; mi < 4; ++mi)
        #pragma unroll
        for (int reg = 0; reg < 4; ++reg) {
            const int i = mi * 4 + reg;
            ull b2 = ((ull)(bb[i] & 0xFFFFFFC0u) << 14) | (ull)((bb[i] & 63u) * 16 + lr);
            ull s2 = ((ull)(ss[i] & 0xFFFFFFC0u) << 14) | (ull)((ss[i] & 63u) * 16 + lr);
            ull t2 = ((ull)(tt[i] & 0xFFFFFFC0u) << 14) | (ull)((tt[i] & 63u) * 16 + lr);
            #pragma unroll
            for (int d = 1; d < 16; d <<= 1) {
                const ull ob = __shfl_xor(b2, d);
                const ull os = __shfl_xor(s2, d);
                const ull ot = __shfl_xor(t2, d);
                const ull x1 = umin64(b2, ob), y1 = umax64(b2, ob);
                const ull x2 = umin64(s2, os), y2 = umax64(s2, os);
                const ull c2 = umin64(y1, x2);
                const ull t1 = umax64(y1, x2);
                const ull c3 = umin64(t1, umin64(y2, umin64(t2, ot)));
                b2 = x1; s2 = c2; t2 = c3;
            }
            if (lr == 0) {
                const int row = mi * 16 + quad * 4 + reg;
                mb[w * 64 + row] = b2;
                ms[w * 64 + row] = s2;
                mt[w * 64 + row] = t2;
            }
        }
    __syncthreads();

    if (t < 64) {
        ull b2 = mb[t], s2 = ms[t], t2 = mt[t];
        #pragma unroll
        for (int ww = 1; ww < 4; ++ww) {
            const ull ob = mb[ww * 64 + t], os = ms[ww * 64 + t], ot = mt[ww * 64 + t];
            const ull x1 = umin64(b2, ob), y1 = umax64(b2, ob);
            const ull x2 = umin64(s2, os), y2 = umax64(s2, os);
            const ull c2 = umin64(y1, x2);
            const ull t1 = umax64(y1, x2);
            const ull c3 = umin64(t1, umin64(y2, umin64(t2, ot)));
            b2 = x1; s2 = c2; t2 = c3;
        }
        const int k1 = (int)(b2 & 16383ull);
        const int k2 = (int)(s2 & 16383ull);
        const float v1 = __uint_as_float((unsigned)(b2 >> 14)) - 512.0f;
        const float v2 = __uint_as_float((unsigned)(s2 >> 14)) - 512.0f;
        const float v3 = __uint_as_float((unsigned)(t2 >> 14)) - 512.0f;
        idx_i[m0 + t] = k1;
        idx_f[m0 + t] = (float)k1;
        atomicAdd(&hist[k1], 1);
        if (v2 - v1 < EPSGAP) {
            if (v3 - v1 < THR3) {
                const int pos = atomicAdd(&flagcnt[1], 1);
                listB[pos] = m0 + t;
                valB[pos] = v1;
            } else {
                const int pos = atomicAdd(&flagcnt[0], 1);
                listA[pos] = m0 + t;
                kkA[pos] = k1 | (k2 << 16);
                valA[pos] = v1;
            }
        }
        float lp = v1 + zsqp[t * 4] + zsqp[t * 4 + 1] + zsqp[t * 4 + 2] + zsqp[t * 4 + 3];
        #pragma unroll
        for (int d = 32; d > 0; d >>= 1) lp += __shfl_down(lp, d);
        if (t == 0) loss_p[blockIdx.x] = lp;
    }
}

// ---------------------------------------------------------------------------
// Kernel 3: two-class fixup — patches idx_i/idx_f/hist/loss_fix.
// (dw comes from post-fixup counting sort; zq from gather.) Reads zf
// coalesced.
__global__ __launch_bounds__(256) void fixup_kernel(
        const float* __restrict__ zf, const float* __restrict__ emb,
        const float* __restrict__ esq, const int* __restrict__ flagcnt,
        const int* __restrict__ listA, const int* __restrict__ kkA,
        const float* __restrict__ valA, const int* __restrict__ listB,
        const float* __restrict__ valB,
        int* __restrict__ idx_i, float* __restrict__ idx_f,
        int* __restrict__ hist, float* __restrict__ loss_fix) {
    __shared__ float zrow[256];
    __shared__ float red1[4], red2[4];
    __shared__ ull red[256];
    const int t = threadIdx.x;
    const int w = t >> 6, lane = t & 63;

    // ---- Phase A: exact 2-way check (k1 vs k2) -------------------------
    const int totalA = flagcnt[0];
    for (int fi = blockIdx.x; fi < totalA; fi += 512) {
        const int n = listA[fi];
        const int kk = kkA[fi];
        const int k1 = kk & 0xFFFF, k2 = kk >> 16;
        const float zv = zf[(size_t)n * Dd + t];
        float c1 = zv * emb[(size_t)k1 * Dd + t];
        float c2 = zv * emb[(size_t)k2 * Dd + t];
        #pragma unroll
        for (int d = 32; d > 0; d >>= 1) {
            c1 += __shfl_xor(c1, d);
            c2 += __shfl_xor(c2, d);
        }
        __syncthreads();
        if (lane == 0) { red1[w] = c1; red2[w] = c2; }
        __syncthreads();
        if (t == 0) {
            const float d1 = esq[k1] - 2.0f * (red1[0] + red1[1] + red1[2] + red1[3]);
            const float d2 = esq[k2] - 2.0f * (red2[0] + red2[1] + red2[2] + red2[3]);
            const ull p1 = ((ull)mono(__float_as_uint(d1)) << 32) | (unsigned)k1;
            const ull p2 = ((ull)mono(__float_as_uint(d2)) << 32) | (unsigned)k2;
            const ull pb = p1 < p2 ? p1 : p2;
            const int knew = (int)(unsigned)(pb & 0xFFFFFFFFull);
            const float vnew = unmono((unsigned)(pb >> 32));
            if (knew != k1) {
                idx_i[n] = knew;
                idx_f[n] = (float)knew;
                atomicSub(&hist[k1], 1);
                atomicAdd(&hist[knew], 1);
            }
            atomicAdd(loss_fix, vnew - valA[fi]);
        }
    }

    // ---- Phase B: full-K exact rescan (rare) ---------------------------
    const int totalB = flagcnt[1];
    for (int fi = blockIdx.x; fi < totalB; fi += 512) {
        const int n = listB[fi];
        __syncthreads();
        zrow[t] = zf[(size_t)n * Dd + t];
        __syncthreads();
        ull best = ~0ull;
        #pragma unroll
        for (int kc = 0; kc < 4; ++kc) {
            const int k = t * 4 + kc;
            const float* ep = emb + (size_t)k * Dd;
            float dot = 0.0f;
            #pragma unroll 8
            for (int c4 = 0; c4 < 64; ++c4) {
                const float4 e4 = *(const float4*)(ep + c4 * 4);
                const float4 z4 = *(const float4*)&zrow[c4 * 4];
                dot = fmaf(z4.x, e4.x, dot);
                dot = fmaf(z4.y, e4.y, dot);
                dot = fmaf(z4.z, e4.z, dot);
                dot = fmaf(z4.w, e4.w, dot);
            }
            const float val = esq[k] - 2.0f * dot;
            const ull pk = ((ull)mono(__float_as_uint(val)) << 32) | (unsigned)k;
            if (pk < best) best = pk;
        }
        red[t] = best;
        __syncthreads();
        for (int s = 128; s > 0; s >>= 1) {
            if (t < s) { if (red[t + s] < red[t]) red[t] = red[t + s]; }
            __syncthreads();
        }
        if (t == 0) {
            const int knew = (int)(unsigned)(red[0] & 0xFFFFFFFFull);
            const float vnew = unmono((unsigned)(red[0] >> 32));
            const int kold = idx_i[n];
            if (knew != kold) {
                idx_i[n] = knew;
                idx_f[n] = (float)knew;
                atomicSub(&hist[kold], 1);
                atomicAdd(&hist[knew], 1);
            }
            atomicAdd(loss_fix, vnew - valB[fi]);
        }
    }
}

// ---------------------------------------------------------------------------
// Kernel 4: hist scan -> cursor + cluster-size EMA/Laplace + loss reduce.
// 1 block, 1024 threads, wave-shuffle (R3-proven).
__global__ void scan_fin1_kernel(const int* __restrict__ hist,
                                 int* __restrict__ cursor,
                                 const float* __restrict__ ema_cs,
                                 const float* __restrict__ loss_p,
                                 const float* __restrict__ loss_fix,
                                 float* __restrict__ cs_out,
                                 float* __restrict__ loss_out) {
    __shared__ int wbase[16];
    __shared__ float wred[16], wred2[16];
    const int t = threadIdx.x;            // 1024 threads = 16 waves
    const int w = t >> 6, lane = t & 63;
    const int v = hist[t];
    int x = v;
    #pragma unroll
    for (int d = 1; d < 64; d <<= 1) {
        const int o = __shfl_up(x, d);
        if (lane >= d) x += o;
    }
    const float csr = ema_cs[t] * DECAY + (1.0f - DECAY) * (float)v;
    float r = csr;
    float r2 = (t < 512) ? loss_p[t] : 0.0f;
    #pragma unroll
    for (int d = 32; d > 0; d >>= 1) { r += __shfl_xor(r, d); r2 += __shfl_xor(r2, d); }
    if (lane == 63) wbase[w] = x;
    if (lane == 0) { wred[w] = r; wred2[w] = r2; }
    __syncthreads();
    if (t < 16) {
        const int own = wbase[t];
        int s = own;
        #pragma unroll
        for (int d = 1; d < 16; d <<= 1) {
            const int o = __shfl_up(s, d);
            if (t >= d) s += o;
        }
        wbase[t] = s - own;
        float rr = wred[t], rr2 = wred2[t];
        #pragma unroll
        for (int d = 1; d < 16; d <<= 1) { rr += __shfl_xor(rr, d); rr2 += __shfl_xor(rr2, d); }
        if (t == 0) { wred[0] = rr; wred2[0] = rr2; }
    }
    __syncthreads();
    cursor[t] = wbase[w] + x - v;
    const float nsum = wred[0];
    const float cs = (csr + EPSV) / (nsum + (float)Kk * EPSV) * nsum;
    cs_out[t] = cs;
    if (t == 0) loss_out[0] = BETA * (wred2[0] + loss_fix[0]) / (float)ZELEM;
}

// ---------------------------------------------------------------------------
// Kernel 5: counting-sort scatter. (R0-proven)
__global__ __launch_bounds__(256) void sort_kernel(
        const int* __restrict__ idx, int* __restrict__ cursor,
        int* __restrict__ sorted, int* __restrict__ codes_sorted) {
    const int n = blockIdx.x * 256 + threadIdx.x;
    const int j = idx[n];
    const int pos = atomicAdd(&cursor[j], 1);
    sorted[pos] = n;
    codes_sorted[pos] = j;
}

// ---------------------------------------------------------------------------
// Kernel 6: balanced segmented reduction -> dw (atomic only at segment
// boundaries ~1.5K total). (R0-proven)
__global__ __launch_bounds__(256) void dw_seg_kernel(
        const float* __restrict__ zf, const int* __restrict__ sorted,
        const int* __restrict__ codes_sorted, float* __restrict__ dw) {
    __shared__ int sid[64];
    __shared__ int scode[65];
    const int t = threadIdx.x;
    const int p0 = blockIdx.x * 64;
    if (t < 64) {
        sid[t] = sorted[p0 + t];
        scode[t] = codes_sorted[p0 + t];
    }
    if (t == 64) scode[64] = -1;
    __syncthreads();
    const int c = t;
    float acc = 0.0f;
    #pragma unroll 8
    for (int p = 0; p < 64; ++p) {
        acc += zf[(size_t)sid[p] * Dd + c];
        if (scode[p] != scode[p + 1]) {
            atomicAdd(&dw[(size_t)scode[p] * Dd + c], acc);
            acc = 0.0f;
        }
    }
}

// ---------------------------------------------------------------------------
// Kernel 7: new_ema_w = EMA(ema_w, dw); new_emb = nw / cs.
// dw aliases new_emb_out (read-then-write same index, same thread).
__global__ __launch_bounds__(256) void finalize2_kernel(
        const float* __restrict__ ema_w, const float* __restrict__ dw,
        const float* __restrict__ cs_out,
        float* __restrict__ new_emb_out, float* __restrict__ new_ema_w_out) {
    const int i = blockIdx.x * 256 + threadIdx.x;
    const float nw = ema_w[i] * DECAY + (1.0f - DECAY) * dw[i];
    const float cs = cs_out[i >> 8];
    new_ema_w_out[i] = nw;
    new_emb_out[i]   = nw / cs;
}

// ---------------------------------------------------------------------------
// Kernel 8: gather z_q in [B,C,HW] layout, overwriting the zf region.
// Runs last (after fixup idx patches + dw_seg zf reads). (R0-proven)
__global__ __launch_bounds__(256) void gather_kernel(
        const float* __restrict__ emb, const int* __restrict__ idx,
        float* __restrict__ zq_out) {
    const int tid = blockIdx.x * 256 + threadIdx.x;
    const int e0 = tid * 4;
    const int c = (e0 >> 10) & 255;
    const int b = e0 >> 18;
    const int n0 = b * 1024 + (e0 & 1023);
    const int4 j4 = *(const int4*)(idx + n0);
    float4 e;
    e.x = emb[(size_t)j4.x * Dd + c];
    e.y = emb[(size_t)j4.y * Dd + c];
    e.z = emb[(size_t)j4.z * Dd + c];
    e.w = emb[(size_t)j4.w * Dd + c];
    *(float4*)(zq_out + e0) = e;
}

// ---------------------------------------------------------------------------
extern "C" void kernel_launch(void* const* d_in, const int* in_sizes, int n_in,
                              void* d_out, int out_size, void* d_ws, size_t ws_size,
                              hipStream_t stream) {
    const float* z      = (const float*)d_in[0];
    const float* emb    = (const float*)d_in[1];
    const float* ema_cs = (const float*)d_in[2];
    const float* ema_w  = (const float*)d_in[3];

    float* out = (float*)d_out;
    float* zq_out        = out;                 // 8388608 (zf staging until gather)
    float* idx_out_f     = out + 8388608;       // 32768
    float* loss_out      = out + 8421376;       // 1
    float* new_emb_out   = out + 8421377;       // 262144 (dw staging)
    float* cs_out        = out + 8683521;       // 1024
    float* new_ema_w_out = out + 8684545;       // 262144

    int*   idx_i    = (int*)d_ws;                    // 32768
    int*   flagcnt  = idx_i + 32768;                 // 16  ([0]=A, [1]=B)
    float* loss_fix = (float*)(flagcnt + 16);        // 16
    int*   listA    = (int*)(loss_fix + 16);         // 32768
    float* valA     = (float*)(listA + 32768);       // 32768
    int*   kkA      = (int*)(valA + 32768);          // 32768
    int*   listB    = kkA + 32768;                   // 32768
    float* valB     = (float*)(listB + 32768);       // 32768
    int*   hist     = (int*)(valB + 32768);          // 1024
    int*   cursor   = hist + 1024;                   // 1024
    int*   sorted   = cursor + 1024;                 // 32768
    int*   codes_s  = sorted + 32768;                // 32768
    float* esq      = (float*)(codes_s + 32768);     // 1024
    float* loss_p   = esq + 1024;                    // 512
    unsigned short* ehg = (unsigned short*)(loss_p + 512);  // 262144 shorts
    unsigned short* elg = ehg + 262144;                     // 262144 shorts

    float* zf = zq_out;        // transposed z staged in zq output region
    float* dw = new_emb_out;   // dw staged in new_embedding output region

    prep_e_kernel<<<64, 256, 0, stream>>>(emb, ehg, elg, esq, hist, flagcnt,
                                          loss_fix, dw);
    dist_kernel<<<Nn / 64, 256, 0, stream>>>(z, ehg, elg, esq, zf, idx_i,
                                             idx_out_f, hist, flagcnt, listA,
                                             kkA, valA, listB, valB, loss_p);
    fixup_kernel<<<512, 256, 0, stream>>>(zf, emb, esq, flagcnt, listA, kkA,
                                          valA, listB, valB, idx_i, idx_out_f,
                                          hist, loss_fix);
    scan_fin1_kernel<<<1, 1024, 0, stream>>>(hist, cursor, ema_cs, loss_p,
                                             loss_fix, cs_out, loss_out);
    sort_kernel<<<Nn / 256, 256, 0, stream>>>(idx_i, cursor, sorted, codes_s);
    dw_seg_kernel<<<Nn / 64, 256, 0, stream>>>(zf, sorted, codes_s, dw);
    finalize2_kernel<<<Kk * Dd / 256, 256, 0, stream>>>(ema_w, dw, cs_out,
                                                        new_emb_out, new_ema_w_out);
    gather_kernel<<<ZELEM / 1024, 256, 0, stream>>>(emb, idx_i, zq_out);
}

// Round 14
// 201.462 us; speedup vs baseline: 1.7126x; 1.2163x over previous
//
#include <hip/hip_runtime.h>

typedef unsigned long long ull;
typedef __attribute__((ext_vector_type(8))) short bf16x8;
typedef __attribute__((ext_vector_type(4))) float f32x4;
typedef __attribute__((ext_vector_type(8))) unsigned short u16x8;

#define DECAY 0.99f
#define BETA 0.25f
#define EPSV 1e-5f
#define EPSGAP 0.0625f
#define THR3 0.03125f

// z: [32, 256, 32, 32] fp32 ; embedding: [1024, 256] ; N = 32*32*32 = 32768
#define Dd 256
#define Kk 1024
#define Nn 32768
#define ZELEM 8388608

__device__ __forceinline__ unsigned short f2bf(float f) {
    unsigned int x = __float_as_uint(f);
    x += 0x7FFFu + ((x >> 16) & 1u);          // RNE
    return (unsigned short)(x >> 16);
}
__device__ __forceinline__ float bf2f(unsigned short b) {
    return __uint_as_float(((unsigned int)b) << 16);
}
__device__ __forceinline__ unsigned mono(unsigned b) {
    return b ^ (((int)b >> 31) | 0x80000000u);   // monotone float->uint
}
__device__ __forceinline__ float unmono(unsigned m) {
    unsigned b = (m & 0x80000000u) ? (m ^ 0x80000000u) : ~m;
    return __uint_as_float(b);
}
__device__ __forceinline__ unsigned umin32(unsigned a, unsigned b) { return a < b ? a : b; }
__device__ __forceinline__ unsigned umax32(unsigned a, unsigned b) { return a > b ? a : b; }
__device__ __forceinline__ ull umin64(ull a, ull b) { return a < b ? a : b; }
__device__ __forceinline__ ull umax64(ull a, ull b) { return a > b ? a : b; }

// ---------------------------------------------------------------------------
// Kernel 1: grid 512.
//  blocks 0..63 : emb hi/lo split + esq + zero hist
//  block 64     : reduce sum(ema_cs) -> nsum  (sum(hist)=32768 invariant)
//  ALL blocks   : zero their slice of the dw replicas
__global__ __launch_bounds__(256) void prep_e_kernel(
        const float* __restrict__ emb, unsigned short* __restrict__ ehg,
        unsigned short* __restrict__ elg, float* __restrict__ esq,
        int* __restrict__ hist, float* __restrict__ nsum,
        const float* __restrict__ ema_cs, float* __restrict__ dwr, int nrep) {
    const int nsub = blockIdx.x;
    const int t = threadIdx.x;
    {
        const int per = nrep * 512;
        float4* dst = (float4*)(dwr + (size_t)nsub * per);
        const int n4 = per >> 2;
        for (int j = t; j < n4; j += 256) dst[j] = make_float4(0.f, 0.f, 0.f, 0.f);
    }
    if (nsub < 64) {
        if (t < 16) hist[nsub * 16 + t] = 0;
        #pragma unroll
        for (int it = 0; it < 2; ++it) {
            const int item = it * 256 + t;
            const int kc = item >> 6, lane = item & 63;
            const int quad = lane >> 4, nl = lane & 15;
            const float* ep = emb + (size_t)(nsub * 16 + nl) * Dd + kc * 32 + quad * 8;
            const float4 a = *(const float4*)ep;
            const float4 b4 = *(const float4*)(ep + 4);
            const float v[8] = {a.x, a.y, a.z, a.w, b4.x, b4.y, b4.z, b4.w};
            u16x8 hi, lo;
            #pragma unroll
            for (int j = 0; j < 8; ++j) {
                const unsigned short h = f2bf(v[j]);
                hi[j] = h;
                lo[j] = f2bf(v[j] - bf2f(h));
            }
            const size_t off = ((size_t)(nsub * 8 + kc) * 64 + lane) * 8;
            *(u16x8*)&ehg[off] = hi;
            *(u16x8*)&elg[off] = lo;
        }
        {
            const int nl = t >> 4, seg = t & 15;
            const float* ep = emb + (size_t)(nsub * 16 + nl) * Dd + seg * 16;
            float s = 0.0f;
            #pragma unroll
            for (int j = 0; j < 4; ++j) {
                const float4 v4 = *(const float4*)(ep + j * 4);
                s += v4.x * v4.x + v4.y * v4.y + v4.z * v4.z + v4.w * v4.w;
            }
            #pragma unroll
            for (int d = 1; d < 16; d <<= 1) s += __shfl_xor(s, d);
            if (seg == 0) esq[nsub * 16 + nl] = s;
        }
    } else if (nsub == 64) {
        __shared__ float wred[4];
        const int w = t >> 6, lane = t & 63;
        float s = ema_cs[t] + ema_cs[t + 256] + ema_cs[t + 512] + ema_cs[t + 768];
        #pragma unroll
        for (int d = 32; d > 0; d >>= 1) s += __shfl_xor(s, d);
        if (lane == 0) wred[w] = s;
        __syncthreads();
        if (t == 0)
            nsum[0] = DECAY * (wred[0] + wred[1] + wred[2] + wred[3])
                      + (1.0f - DECAY) * (float)Nn;
    }
}

// ---------------------------------------------------------------------------
// Kernel 2: EVERYTHING per 64-point tile in one kernel:
//  MFMA 3-pass distances + top-3 argmin
//  INLINE fixup (A: exact 2-way via zh/zl reconstruct; B: full-K rescan)
//    -> kidx/vv corrected BEFORE hist/idx/loss/zq/dw, so no patches anywhere
//  hist atomics + idx/loss + z_q store (LDS emb gather) + dw (end-placed,
//  replicated atomics, z re-read, no trailing barrier)
// R14 FIX: staged-layout reconstruction index — chunk = (c>>3) ^ (p&7) with
// FULL 5-bit chunk id: ((t>>3) ^ (p&7)) << 3. R13's `((t>>3)^p)&7` dropped
// chunk bits 3-4 -> garbage z for channels >= 64 -> wrong fixup codes.
__global__ __launch_bounds__(256) void dist_kernel(
        const float* __restrict__ z, const unsigned short* __restrict__ ehg,
        const unsigned short* __restrict__ elg, const float* __restrict__ esq,
        const float* __restrict__ emb,
        float* __restrict__ zq, float* __restrict__ dwr, int repmask,
        int* __restrict__ idx_i, float* __restrict__ idx_f,
        int* __restrict__ hist, float* __restrict__ loss_p) {
    __shared__ __align__(16) unsigned char smem[72704];
    __shared__ int kidx[64];
    __shared__ float vv[64];
    __shared__ int aList[64], bList[64];
    __shared__ int acnt, bcnt;
    __shared__ float red1[4], red2[4];
    __shared__ ull bred[4];
    unsigned short* zh = (unsigned short*)smem;            // 32KB
    unsigned short* zl = (unsigned short*)(smem + 32768);  // 32KB
    ull* mb   = (ull*)(smem + 65536);                      // 2KB (merge; reused: zrowF)
    ull* ms   = (ull*)(smem + 67584);                      // 2KB (merge)
    float* zsqp = (float*)(smem + 69632);                  // 1KB
    ull* mt   = (ull*)(smem + 70656);                      // 2KB (top-3 merge)
    float* zrowF = (float*)mb;                             // 1KB reuse (B-phase)
    float* eldsf = (float*)smem;                           // [64][257] f32 (65792B) aliases zh/zl/mb — dead by then

    const int t = threadIdx.x, w = t >> 6, L = t & 63;
    const int quad = L >> 4, lr = L & 15;
    const int m0 = blockIdx.x * 64;
    const int b = m0 >> 10, hw0 = m0 & 1023;

    if (t == 0) { acnt = 0; bcnt = 0; }

    // ---- stage: wave w converts channels w*64..+63 for all 64 points
    {
        const int c0 = w * 64;
        const float* zp = z + (size_t)b * 262144 + hw0 + L;
        float s = 0.0f;
        #pragma unroll
        for (int cg = 0; cg < 8; ++cg) {
            float v[8];
            #pragma unroll
            for (int j = 0; j < 8; ++j)
                v[j] = zp[(size_t)(c0 + cg * 8 + j) * 1024];
            u16x8 hi, lo;
            #pragma unroll
            for (int j = 0; j < 8; ++j) {
                s = fmaf(v[j], v[j], s);
                const unsigned short h = f2bf(v[j]);
                hi[j] = h;
                lo[j] = f2bf(v[j] - bf2f(h));
            }
            const int chunk = ((c0 >> 3) + cg) ^ (L & 7);
            *(u16x8*)&zh[L * 256 + chunk * 8] = hi;
            *(u16x8*)&zl[L * 256 + chunk * 8] = lo;
        }
        zsqp[L * 4 + w] = s;
    }
    __syncthreads();

    const unsigned short* ehw = ehg + (size_t)(w * 1024 + L) * 8;
    const unsigned short* elw = elg + (size_t)(w * 1024 + L) * 8;

    unsigned bb[16], ss[16], tt[16];
    #pragma unroll
    for (int i = 0; i < 16; ++i) { bb[i] = 0xFFFFFFFFu; ss[i] = 0xFFFFFFFFu; tt[i] = 0xFFFFFFFFu; }

    bf16x8 Bh[2][2], Bl[2][2];
    #pragma unroll
    for (int ni = 0; ni < 2; ++ni) {
        Bh[0][ni] = *(const bf16x8*)(ehw + (size_t)ni * 4096);
        Bl[0][ni] = *(const bf16x8*)(elw + (size_t)ni * 4096);
    }
    bf16x8 Ah[2][4], Al[2][4];
    #pragma unroll
    for (int mi = 0; mi < 4; ++mi) {
        const int chunk = quad ^ (lr & 7);               // kc = 0
        const int o = (mi * 16 + lr) * 256 + chunk * 8;
        Ah[0][mi] = *(const bf16x8*)&zh[o];
        Al[0][mi] = *(const bf16x8*)&zl[o];
    }

    for (int nt = 0; nt < 8; ++nt) {
        f32x4 acc[4][2];
        #pragma unroll
        for (int mi = 0; mi < 4; ++mi)
            #pragma unroll
            for (int ni = 0; ni < 2; ++ni) acc[mi][ni] = (f32x4){0.f, 0.f, 0.f, 0.f};

        #pragma unroll
        for (int kc = 0; kc < 8; ++kc) {
            const int cur = kc & 1, nxt = cur ^ 1;
            const int nkc = (kc + 1) & 7;
            const int nnt = (kc == 7) ? ((nt + 1) & 7) : nt;
            #pragma unroll
            for (int ni = 0; ni < 2; ++ni) {
                const size_t o = (size_t)nnt * 32768 + (size_t)ni * 4096 + (size_t)nkc * 512;
                Bh[nxt][ni] = *(const bf16x8*)(ehw + o);
                Bl[nxt][ni] = *(const bf16x8*)(elw + o);
            }
            #pragma unroll
            for (int mi = 0; mi < 4; ++mi) {
                const int chunk = (nkc * 4 + quad) ^ (lr & 7);
                const int o = (mi * 16 + lr) * 256 + chunk * 8;
                Ah[nxt][mi] = *(const bf16x8*)&zh[o];
                Al[nxt][mi] = *(const bf16x8*)&zl[o];
            }
            __builtin_amdgcn_s_setprio(1);
            #pragma unroll
            for (int mi = 0; mi < 4; ++mi)
                #pragma unroll
                for (int ni = 0; ni < 2; ++ni) {
                    acc[mi][ni] = __builtin_amdgcn_mfma_f32_16x16x32_bf16(Ah[cur][mi], Bh[cur][ni], acc[mi][ni], 0, 0, 0);
                    acc[mi][ni] = __builtin_amdgcn_mfma_f32_16x16x32_bf16(Ah[cur][mi], Bl[cur][ni], acc[mi][ni], 0, 0, 0);
                    acc[mi][ni] = __builtin_amdgcn_mfma_f32_16x16x32_bf16(Al[cur][mi], Bh[cur][ni], acc[mi][ni], 0, 0, 0);
                }
            __builtin_amdgcn_s_setprio(0);
        }
        const int q0 = nt * 8 + w * 2;
        const float e0b = esq[q0 * 16 + lr] + 512.0f;
        const float e1b = esq[(q0 + 1) * 16 + lr] + 512.0f;
        #pragma unroll
        for (int mi = 0; mi < 4; ++mi)
            #pragma unroll
            for (int reg = 0; reg < 4; ++reg) {
                const int i = mi * 4 + reg;
                #pragma unroll
                for (int ni = 0; ni < 2; ++ni) {
                    const float val = fmaf(-2.0f, acc[mi][ni][reg], ni ? e1b : e0b);
                    const unsigned pk = (__float_as_uint(val) & 0xFFFFFFC0u) | (unsigned)(q0 + ni);
                    const unsigned m1 = umin32(bb[i], pk), M1 = umax32(bb[i], pk);
                    const unsigned m2 = umin32(ss[i], M1), M2 = umax32(ss[i], M1);
                    const unsigned m3 = umin32(tt[i], M2);
                    bb[i] = m1; ss[i] = m2; tt[i] = m3;
                }
            }
    }

    #pragma unroll
    for (int mi = 0; mi < 4; ++mi)
        #pragma unroll
        for (int reg = 0; reg < 4; ++reg) {
            const int i = mi * 4 + reg;
            ull b2 = ((ull)(bb[i] & 0xFFFFFFC0u) << 14) | (ull)((bb[i] & 63u) * 16 + lr);
            ull s2 = ((ull)(ss[i] & 0xFFFFFFC0u) << 14) | (ull)((ss[i] & 63u) * 16 + lr);
            ull t2 = ((ull)(tt[i] & 0xFFFFFFC0u) << 14) | (ull)((tt[i] & 63u) * 16 + lr);
            #pragma unroll
            for (int d = 1; d < 16; d <<= 1) {
                const ull ob = __shfl_xor(b2, d);
                const ull os = __shfl_xor(s2, d);
                const ull ot = __shfl_xor(t2, d);
                const ull x1 = umin64(b2, ob), y1 = umax64(b2, ob);
                const ull x2 = umin64(s2, os), y2 = umax64(s2, os);
                const ull c2 = umin64(y1, x2);
                const ull t1 = umax64(y1, x2);
                const ull c3 = umin64(t1, umin64(y2, umin64(t2, ot)));
                b2 = x1; s2 = c2; t2 = c3;
            }
            if (lr == 0) {
                const int row = mi * 16 + quad * 4 + reg;
                mb[w * 64 + row] = b2;
                ms[w * 64 + row] = s2;
                mt[w * 64 + row] = t2;
            }
        }
    __syncthreads();

    if (t < 64) {
        ull b2 = mb[t], s2 = ms[t], t2 = mt[t];
        #pragma unroll
        for (int ww = 1; ww < 4; ++ww) {
            const ull ob = mb[ww * 64 + t], os = ms[ww * 64 + t], ot = mt[ww * 64 + t];
            const ull x1 = umin64(b2, ob), y1 = umax64(b2, ob);
            const ull x2 = umin64(s2, os), y2 = umax64(s2, os);
            const ull c2 = umin64(y1, x2);
            const ull t1 = umax64(y1, x2);
            const ull c3 = umin64(t1, umin64(y2, umin64(t2, ot)));
            b2 = x1; s2 = c2; t2 = c3;
        }
        const int k1 = (int)(b2 & 16383ull);
        const int k2 = (int)(s2 & 16383ull);
        const float v1 = __uint_as_float((unsigned)(b2 >> 14)) - 512.0f;
        const float v2 = __uint_as_float((unsigned)(s2 >> 14)) - 512.0f;
        const float v3 = __uint_as_float((unsigned)(t2 >> 14)) - 512.0f;
        kidx[t] = k1;
        vv[t] = v1;
        if (v2 - v1 < EPSGAP) {
            if (v3 - v1 < THR3) bList[atomicAdd(&bcnt, 1)] = t;
            else                aList[atomicAdd(&acnt, 1)] = t | (k2 << 8);
        }
    }
    __syncthreads();

    // ---- INLINE fixup A: exact 2-way check via zh/zl reconstruction ----
    const int nA = acnt, nB = bcnt;
    for (int i = 0; i < nA; ++i) {
        const int e = aList[i];
        const int p = e & 63, k2p = e >> 8;
        const int k1p = kidx[p];
        const int a = p * 256 + (((t >> 3) ^ (p & 7)) << 3) + (t & 7);
        const float zv = bf2f(zh[a]) + bf2f(zl[a]);
        float c1 = zv * emb[(size_t)k1p * Dd + t];
        float c2 = zv * emb[(size_t)k2p * Dd + t];
        #pragma unroll
        for (int d = 32; d > 0; d >>= 1) {
            c1 += __shfl_xor(c1, d);
            c2 += __shfl_xor(c2, d);
        }
        if (L == 0) { red1[w] = c1; red2[w] = c2; }
        __syncthreads();
        if (t == 0) {
            const float d1 = esq[k1p] - 2.0f * (red1[0] + red1[1] + red1[2] + red1[3]);
            const float d2 = esq[k2p] - 2.0f * (red2[0] + red2[1] + red2[2] + red2[3]);
            if (d2 < d1 || (d2 == d1 && k2p < k1p)) { kidx[p] = k2p; vv[p] = d2; }
            else                                     { vv[p] = d1; }
        }
        __syncthreads();
    }

    // ---- INLINE fixup B: full-K exact rescan (rare) --------------------
    for (int i = 0; i < nB; ++i) {
        const int p = bList[i];
        {
            const int a = p * 256 + (((t >> 3) ^ (p & 7)) << 3) + (t & 7);
            zrowF[t] = bf2f(zh[a]) + bf2f(zl[a]);
        }
        __syncthreads();
        ull best = ~0ull;
        #pragma unroll
        for (int kc = 0; kc < 4; ++kc) {
            const int k = t * 4 + kc;
            const float* ep = emb + (size_t)k * Dd;
            float dot = 0.0f;
            #pragma unroll 8
            for (int c4 = 0; c4 < 64; ++c4) {
                const float4 e4 = *(const float4*)(ep + c4 * 4);
                const float4 z4 = *(const float4*)&zrowF[c4 * 4];
                dot = fmaf(z4.x, e4.x, dot);
                dot = fmaf(z4.y, e4.y, dot);
                dot = fmaf(z4.z, e4.z, dot);
                dot = fmaf(z4.w, e4.w, dot);
            }
            const float val = esq[k] - 2.0f * dot;
            const ull pk = ((ull)mono(__float_as_uint(val)) << 32) | (unsigned)k;
            if (pk < best) best = pk;
        }
        #pragma unroll
        for (int d = 32; d > 0; d >>= 1) {
            const ull o = __shfl_xor(best, d);
            best = o < best ? o : best;
        }
        if (L == 0) bred[w] = best;
        __syncthreads();
        if (t == 0) {
            ull bbx = bred[0];
            bbx = umin64(bbx, bred[1]);
            bbx = umin64(bbx, bred[2]);
            bbx = umin64(bbx, bred[3]);
            kidx[p] = (int)(unsigned)(bbx & 0xFFFFFFFFull);
            vv[p] = unmono((unsigned)(bbx >> 32));
        }
        __syncthreads();
    }

    // ---- hist + idx + loss (corrected kidx/vv) -------------------------
    if (t < 64) {
        const int k = kidx[t];
        idx_i[m0 + t] = k;
        idx_f[m0 + t] = (float)k;
        atomicAdd(&hist[k], 1);
        float lp = vv[t] + zsqp[t * 4] + zsqp[t * 4 + 1] + zsqp[t * 4 + 2] + zsqp[t * 4 + 3];
        #pragma unroll
        for (int d = 32; d > 0; d >>= 1) lp += __shfl_down(lp, d);
        if (t == 0) loss_p[blockIdx.x] = lp;
    }
    __syncthreads();

    // ---- emb-load: the 64 (corrected) code rows into eldsf[64][257] ----
    for (int pr = w; pr < 64; pr += 4) {
        const float* er = emb + (size_t)kidx[pr] * Dd;
        #pragma unroll
        for (int g = 0; g < 4; ++g)
            eldsf[pr * 257 + g * 64 + L] = er[g * 64 + L];
    }
    __syncthreads();

    // ---- z_q store: [B,C,HW] layout, coalesced float4 over hw ----------
    {
        const int g = t & 15;
        const int cl = t >> 4;
        float* zqb = zq + (size_t)b * 262144 + hw0 + g * 4;
        #pragma unroll
        for (int pass = 0; pass < 16; ++pass) {
            const int c = pass * 16 + cl;
            float4 v;
            v.x = eldsf[(g * 4 + 0) * 257 + c];
            v.y = eldsf[(g * 4 + 1) * 257 + c];
            v.z = eldsf[(g * 4 + 2) * 257 + c];
            v.w = eldsf[(g * 4 + 3) * 257 + c];
            *(float4*)(zqb + (size_t)c * 1024) = v;
        }
    }

    // ---- dw (LAST, no trailing barrier): z re-read + replicated atomics
    {
        const int c = t;
        const float* zcol = z + (size_t)b * 262144 + (size_t)c * 1024 + hw0;
        float* dwb = dwr + (size_t)(blockIdx.x & repmask) * (Kk * Dd);
        #pragma unroll 4
        for (int p = 0; p < 64; ++p) {
            atomicAdd(&dwb[(size_t)kidx[p] * Dd + c], zcol[p]);
        }
    }
}

// ---------------------------------------------------------------------------
// Kernel 3: finalize — one block per code k. cs[k] local (nsum precomputed,
// sum(hist)=32768 invariant holds post-inline-fixup), sums dw replicas,
// EMA + divide. Block 0 reduces the loss (vv already exact; no loss_fix).
__global__ __launch_bounds__(256) void finalize2_kernel(
        const float* __restrict__ ema_w, const float* __restrict__ dwr,
        int nrep, const int* __restrict__ hist,
        const float* __restrict__ ema_cs, const float* __restrict__ nsum,
        const float* __restrict__ loss_p,
        float* __restrict__ cs_out, float* __restrict__ loss_out,
        float* __restrict__ new_emb_out, float* __restrict__ new_ema_w_out) {
    const int k = blockIdx.x;
    const int t = threadIdx.x;
    const float n = nsum[0];
    const float csr = ema_cs[k] * DECAY + (1.0f - DECAY) * (float)hist[k];
    const float cs = (csr + EPSV) / (n + (float)Kk * EPSV) * n;
    if (t == 0) cs_out[k] = cs;
    const int i = k * 256 + t;
    float s = 0.0f;
    for (int r = 0; r < nrep; ++r) s += dwr[(size_t)r * (Kk * Dd) + i];
    const float nw = ema_w[i] * DECAY + (1.0f - DECAY) * s;
    new_ema_w_out[i] = nw;
    new_emb_out[i]   = nw / cs;
    if (k == 0) {
        __shared__ float wred[4];
        const int w = t >> 6, lane = t & 63;
        float r2 = loss_p[t] + loss_p[t + 256];
        #pragma unroll
        for (int d = 32; d > 0; d >>= 1) r2 += __shfl_xor(r2, d);
        if (lane == 0) wred[w] = r2;
        __syncthreads();
        if (t == 0)
            loss_out[0] = BETA * (wred[0] + wred[1] + wred[2] + wred[3]) / (float)ZELEM;
    }
}

// ---------------------------------------------------------------------------
extern "C" void kernel_launch(void* const* d_in, const int* in_sizes, int n_in,
                              void* d_out, int out_size, void* d_ws, size_t ws_size,
                              hipStream_t stream) {
    const float* z      = (const float*)d_in[0];
    const float* emb    = (const float*)d_in[1];
    const float* ema_cs = (const float*)d_in[2];
    const float* ema_w  = (const float*)d_in[3];

    float* out = (float*)d_out;
    float* zq_out        = out;                 // 8388608 (z_q written directly by dist)
    float* idx_out_f     = out + 8388608;       // 32768
    float* loss_out      = out + 8421376;       // 1
    float* new_emb_out   = out + 8421377;       // 262144
    float* cs_out        = out + 8683521;       // 1024
    float* new_ema_w_out = out + 8684545;       // 262144

    int*   idx_i    = (int*)d_ws;                    // 32768
    int*   hist     = idx_i + 32768;                 // 1024
    float* esq      = (float*)(hist + 1024);         // 1024
    float* loss_p   = esq + 1024;                    // 512
    float* nsum     = loss_p + 512;                  // 16
    unsigned short* ehg = (unsigned short*)(nsum + 16);     // 262144 shorts
    unsigned short* elg = ehg + 262144;                     // 262144 shorts
    // dw replicas: after elg, 256B-aligned
    size_t dwr_off = ((size_t)((char*)(elg + 262144) - (char*)d_ws) + 255) & ~(size_t)255;
    float* dwr = (float*)((char*)d_ws + dwr_off);
    const size_t repbytes = (size_t)Kk * Dd * 4;     // 1MB per replica
    size_t rem = (ws_size > dwr_off) ? ws_size - dwr_off : 0;
    int nrep = 1;
    while (nrep < 8 && (size_t)(nrep * 2) * repbytes <= rem) nrep <<= 1;

    prep_e_kernel<<<512, 256, 0, stream>>>(emb, ehg, elg, esq, hist, nsum,
                                           ema_cs, dwr, nrep);
    dist_kernel<<<Nn / 64, 256, 0, stream>>>(z, ehg, elg, esq, emb, zq_out,
                                             dwr, nrep - 1, idx_i, idx_out_f,
                                             hist, loss_p);
    finalize2_kernel<<<Kk, 256, 0, stream>>>(ema_w, dwr, nrep, hist, ema_cs,
                                             nsum, loss_p, cs_out, loss_out,
                                             new_emb_out, new_ema_w_out);
}